// Round 1
// baseline (786.420 us; speedup 1.0000x reference)
//
#include <hip/hip_runtime.h>

// VGAE on MI355X — round 0: correct f32 baseline.
// Pipeline:
//   deg (atomic) -> dis=rsqrt -> norm[e]=dis[row]*ew*dis[col]
//   hw1 = x@W1                                    (f32 LDS-tiled GEMM)
//   h    = dis^2*hw1 + b1  +  scatter norm*hw1[row] -> col   (pre-relu)
//   hagg = dis^2*relu(h) + scatter norm*relu(h[row]) -> col  (shared by conv2/conv3)
//   [mean|lstd] = hagg @ [W2|W3] + [b2|b3]        (fused GEMM)
//   z = mean + noise*exp(lstd)
//   out = sigmoid(z @ z^T)                        (128x128 tile, 8x8/thread)
// Scratch: dis/norm/z in d_ws (~3.3 MB); hw1/h/hagg/mean/lstd live in d_out's
// 400 MB (decode reads only z and rewrites all of d_out last).

#define Nn 10000

static __device__ __forceinline__ float sigmoidf(float v) {
  return 1.0f / (1.0f + __expf(-v));
}

__global__ void k_deg_init(float* __restrict__ deg, int n) {
  int i = blockIdx.x * 256 + threadIdx.x;
  if (i < n) deg[i] = 1.0f;  // self-loop weight
}

__global__ void k_deg_scatter(const int* __restrict__ col, const float* __restrict__ ew,
                              float* __restrict__ deg, int E) {
  int e = blockIdx.x * 256 + threadIdx.x;
  if (e < E) atomicAdd(&deg[col[e]], ew[e]);
}

__global__ void k_dis(float* __restrict__ deg, int n) {
  int i = blockIdx.x * 256 + threadIdx.x;
  if (i < n) { float d = deg[i]; deg[i] = (d > 0.0f) ? rsqrtf(d) : 0.0f; }
}

__global__ void k_norm(const int* __restrict__ row, const int* __restrict__ col,
                       const float* __restrict__ ew, const float* __restrict__ dis,
                       float* __restrict__ nrm, int E) {
  int e = blockIdx.x * 256 + threadIdx.x;
  if (e < E) nrm[e] = dis[row[e]] * ew[e] * dis[col[e]];
}

// hw1 = x[10000,256] @ W1[256,128].  Block: 16 rows x 128 cols, 256 threads,
// each thread 2 rows x 4 cols. K-tiles of 64 staged in LDS.
__global__ __launch_bounds__(256) void k_gemm1(const float* __restrict__ x,
                                               const float* __restrict__ W1,
                                               float* __restrict__ hw1) {
  __shared__ float xs[16][68];    // row stride 272 B (16B-aligned), bank-safe
  __shared__ float ws[64][128];
  const int tid = threadIdx.x;
  const int row0 = blockIdx.x * 16;
  const int j0 = (tid & 31) * 4;
  const int r0 = (tid >> 5) * 2;
  const int lr = tid >> 4, lk = tid & 15;
  float acc0[4] = {0, 0, 0, 0}, acc1[4] = {0, 0, 0, 0};
  for (int k0 = 0; k0 < 256; k0 += 64) {
    *(float4*)&xs[lr][lk * 4] = *(const float4*)&x[(row0 + lr) * 256 + k0 + lk * 4];
#pragma unroll
    for (int it = 0; it < 8; ++it) {
      int idx4 = tid + it * 256;
      int kk = idx4 >> 5, jq = idx4 & 31;
      *(float4*)&ws[kk][jq * 4] = *(const float4*)&W1[(k0 + kk) * 128 + jq * 4];
    }
    __syncthreads();
#pragma unroll 8
    for (int kk = 0; kk < 64; ++kk) {
      float a0 = xs[r0][kk], a1 = xs[r0 + 1][kk];
      float4 w = *(const float4*)&ws[kk][j0];
      acc0[0] += a0 * w.x; acc0[1] += a0 * w.y; acc0[2] += a0 * w.z; acc0[3] += a0 * w.w;
      acc1[0] += a1 * w.x; acc1[1] += a1 * w.y; acc1[2] += a1 * w.z; acc1[3] += a1 * w.w;
    }
    __syncthreads();
  }
  *(float4*)&hw1[(row0 + r0) * 128 + j0] = make_float4(acc0[0], acc0[1], acc0[2], acc0[3]);
  *(float4*)&hw1[(row0 + r0 + 1) * 128 + j0] = make_float4(acc1[0], acc1[1], acc1[2], acc1[3]);
}

__global__ void k_init_h(const float* __restrict__ hw1, const float* __restrict__ dis,
                         const float* __restrict__ b1, float* __restrict__ h) {
  int idx = blockIdx.x * 256 + threadIdx.x;
  if (idx < Nn * 128) {
    int i = idx >> 7, f = idx & 127;
    float d = dis[i];
    h[idx] = d * d * hw1[idx] + b1[f];  // self-loop norm = dis^2
  }
}

__global__ void k_init_hagg(const float* __restrict__ h, const float* __restrict__ dis,
                            float* __restrict__ hagg) {
  int idx = blockIdx.x * 256 + threadIdx.x;
  if (idx < Nn * 128) {
    int i = idx >> 7;
    float d = dis[i];
    hagg[idx] = d * d * fmaxf(h[idx], 0.0f);
  }
}

// dst[col[e],f] += norm[e] * (relu?)(src[row[e],f]); 2 edges per 256-thread block.
__global__ void k_scatter128(const int* __restrict__ row, const int* __restrict__ col,
                             const float* __restrict__ nrm, const float* __restrict__ src,
                             float* __restrict__ dst, int E, int do_relu) {
  int t = threadIdx.x;
  int e = blockIdx.x * 2 + (t >> 7);
  int f = t & 127;
  if (e < E) {
    float v = src[row[e] * 128 + f];
    if (do_relu) v = fmaxf(v, 0.0f);
    atomicAdd(&dst[col[e] * 128 + f], nrm[e] * v);
  }
}

// [mean|lstd] = hagg[10000,128] @ [W2|W3][128,128] + [b2|b3]
__global__ __launch_bounds__(256) void k_gemm2(const float* __restrict__ hagg,
                                               const float* __restrict__ W2, const float* __restrict__ W3,
                                               const float* __restrict__ b2, const float* __restrict__ b3,
                                               float* __restrict__ mean, float* __restrict__ lstd) {
  __shared__ float xs[16][68];
  __shared__ float ws[64][128];
  const int tid = threadIdx.x;
  const int row0 = blockIdx.x * 16;
  const int j0 = (tid & 31) * 4;
  const int r0 = (tid >> 5) * 2;
  const int lr = tid >> 4, lk = tid & 15;
  float acc0[4] = {0, 0, 0, 0}, acc1[4] = {0, 0, 0, 0};
  for (int k0 = 0; k0 < 128; k0 += 64) {
    *(float4*)&xs[lr][lk * 4] = *(const float4*)&hagg[(row0 + lr) * 128 + k0 + lk * 4];
#pragma unroll
    for (int it = 0; it < 8; ++it) {
      int idx4 = tid + it * 256;
      int kk = idx4 >> 5, jq = idx4 & 31;
      int j = jq * 4;
      float4 wv;
      if (j < 64) wv = *(const float4*)&W2[(k0 + kk) * 64 + j];
      else        wv = *(const float4*)&W3[(k0 + kk) * 64 + (j - 64)];
      *(float4*)&ws[kk][j] = wv;
    }
    __syncthreads();
#pragma unroll 8
    for (int kk = 0; kk < 64; ++kk) {
      float a0 = xs[r0][kk], a1 = xs[r0 + 1][kk];
      float4 w = *(const float4*)&ws[kk][j0];
      acc0[0] += a0 * w.x; acc0[1] += a0 * w.y; acc0[2] += a0 * w.z; acc0[3] += a0 * w.w;
      acc1[0] += a1 * w.x; acc1[1] += a1 * w.y; acc1[2] += a1 * w.z; acc1[3] += a1 * w.w;
    }
    __syncthreads();
  }
  if (j0 < 64) {
    float4 bb = *(const float4*)&b2[j0];
    *(float4*)&mean[(row0 + r0) * 64 + j0] =
        make_float4(acc0[0] + bb.x, acc0[1] + bb.y, acc0[2] + bb.z, acc0[3] + bb.w);
    *(float4*)&mean[(row0 + r0 + 1) * 64 + j0] =
        make_float4(acc1[0] + bb.x, acc1[1] + bb.y, acc1[2] + bb.z, acc1[3] + bb.w);
  } else {
    int j = j0 - 64;
    float4 bb = *(const float4*)&b3[j];
    *(float4*)&lstd[(row0 + r0) * 64 + j] =
        make_float4(acc0[0] + bb.x, acc0[1] + bb.y, acc0[2] + bb.z, acc0[3] + bb.w);
    *(float4*)&lstd[(row0 + r0 + 1) * 64 + j] =
        make_float4(acc1[0] + bb.x, acc1[1] + bb.y, acc1[2] + bb.z, acc1[3] + bb.w);
  }
}

__global__ void k_z(const float* __restrict__ mean, const float* __restrict__ lstd,
                    const float* __restrict__ noise, float* __restrict__ z) {
  int idx = blockIdx.x * 256 + threadIdx.x;
  if (idx < Nn * 64) z[idx] = mean[idx] + noise[idx] * expf(lstd[idx]);
}

// out = sigmoid(z @ z^T). Block: 128x128 tile, 256 threads, 8x8 per thread, K=64.
__global__ __launch_bounds__(256) void k_decode(const float* __restrict__ z,
                                                float* __restrict__ out, int n) {
  __shared__ float zr[128][33];   // [row][k], pad 33: compute-read bank = (8cg+m+kk)%32 -> <=4-way
  __shared__ float zc[128][33];
  const int tid = threadIdx.x;
  const int rows0 = blockIdx.y * 128;
  const int cols0 = blockIdx.x * 128;
  const int r0 = (tid >> 4) * 8;
  const int c0 = (tid & 15) * 8;
  float acc[8][8] = {};
  for (int k0 = 0; k0 < 64; k0 += 32) {
#pragma unroll
    for (int it = 0; it < 4; ++it) {
      int idx4 = tid + it * 256;       // 1024 float4s = 128 rows x 8 quads
      int r = idx4 >> 3, kq = idx4 & 7;
      float4 v = make_float4(0, 0, 0, 0), w = make_float4(0, 0, 0, 0);
      int gr = rows0 + r, gc = cols0 + r;
      if (gr < n) v = *(const float4*)&z[gr * 64 + k0 + kq * 4];
      if (gc < n) w = *(const float4*)&z[gc * 64 + k0 + kq * 4];
      zr[r][kq * 4 + 0] = v.x; zr[r][kq * 4 + 1] = v.y;
      zr[r][kq * 4 + 2] = v.z; zr[r][kq * 4 + 3] = v.w;
      zc[r][kq * 4 + 0] = w.x; zc[r][kq * 4 + 1] = w.y;
      zc[r][kq * 4 + 2] = w.z; zc[r][kq * 4 + 3] = w.w;
    }
    __syncthreads();
#pragma unroll 4
    for (int kk = 0; kk < 32; ++kk) {
      float a[8], b[8];
#pragma unroll
      for (int i = 0; i < 8; ++i) a[i] = zr[r0 + i][kk];
#pragma unroll
      for (int j = 0; j < 8; ++j) b[j] = zc[c0 + j][kk];
#pragma unroll
      for (int i = 0; i < 8; ++i)
#pragma unroll
        for (int j = 0; j < 8; ++j) acc[i][j] += a[i] * b[j];
    }
    __syncthreads();
  }
#pragma unroll
  for (int i = 0; i < 8; ++i) {
    int gr = rows0 + r0 + i;
    if (gr >= n) continue;
    size_t rowoff = (size_t)gr * n;
#pragma unroll
    for (int jq = 0; jq < 2; ++jq) {
      int gc = cols0 + c0 + jq * 4;
      if (gc + 3 < n) {
        float4 o = make_float4(sigmoidf(acc[i][jq * 4 + 0]), sigmoidf(acc[i][jq * 4 + 1]),
                               sigmoidf(acc[i][jq * 4 + 2]), sigmoidf(acc[i][jq * 4 + 3]));
        *(float4*)&out[rowoff + gc] = o;
      } else {
#pragma unroll
        for (int m = 0; m < 4; ++m)
          if (gc + m < n) out[rowoff + gc + m] = sigmoidf(acc[i][jq * 4 + m]);
      }
    }
  }
}

extern "C" void kernel_launch(void* const* d_in, const int* in_sizes, int n_in,
                              void* d_out, int out_size, void* d_ws, size_t ws_size,
                              hipStream_t stream) {
  const float* x     = (const float*)d_in[0];
  const int*   ei    = (const int*)d_in[1];
  const float* ew    = (const float*)d_in[2];
  const float* noise = (const float*)d_in[3];
  const float* W1    = (const float*)d_in[4];
  const float* b1    = (const float*)d_in[5];
  const float* W2    = (const float*)d_in[6];
  const float* b2    = (const float*)d_in[7];
  const float* W3    = (const float*)d_in[8];
  const float* b3    = (const float*)d_in[9];
  const int E = in_sizes[2];
  const int n = Nn;
  const int* row = ei;
  const int* col = ei + E;

  // small scratch in d_ws (~3.3 MB)
  float* wsf = (float*)d_ws;
  float* dis = wsf;                    // n (holds deg, then dis in-place)
  float* nrm = wsf + 10240;            // E
  float* z   = wsf + 10240 + 160000;   // n*64  (16B-aligned: offset 170240 % 4 == 0)

  // big intermediates live in d_out (decode reads only z, then rewrites all of d_out)
  float* S    = (float*)d_out;
  float* hw1  = S;                     // n*128
  float* h    = S + 1310720;           // n*128
  float* hagg = S + 2621440;           // n*128
  float* mean = S + 3932160;           // n*64
  float* lstd = S + 4587520;           // n*64

  k_deg_init<<<(n + 255) / 256, 256, 0, stream>>>(dis, n);
  k_deg_scatter<<<(E + 255) / 256, 256, 0, stream>>>(col, ew, dis, E);
  k_dis<<<(n + 255) / 256, 256, 0, stream>>>(dis, n);
  k_norm<<<(E + 255) / 256, 256, 0, stream>>>(row, col, ew, dis, nrm, E);

  k_gemm1<<<n / 16, 256, 0, stream>>>(x, W1, hw1);
  k_init_h<<<(n * 128 + 255) / 256, 256, 0, stream>>>(hw1, dis, b1, h);
  k_scatter128<<<(E + 1) / 2, 256, 0, stream>>>(row, col, nrm, hw1, h, E, 0);

  k_init_hagg<<<(n * 128 + 255) / 256, 256, 0, stream>>>(h, dis, hagg);
  k_scatter128<<<(E + 1) / 2, 256, 0, stream>>>(row, col, nrm, h, hagg, E, 1);

  k_gemm2<<<n / 16, 256, 0, stream>>>(hagg, W2, W3, b2, b3, mean, lstd);
  k_z<<<(n * 64 + 255) / 256, 256, 0, stream>>>(mean, lstd, noise, z);

  dim3 g((n + 127) / 128, (n + 127) / 128);
  k_decode<<<g, 256, 0, stream>>>(z, (float*)d_out, n);
}

// Round 2
// 621.010 us; speedup vs baseline: 1.2664x; 1.2664x over previous
//
#include <hip/hip_runtime.h>

// VGAE on MI355X — round 2: CSR gather aggregation + split-bf16 MFMA decode.
// Pipeline:
//   deg/cnt (atomic) -> dis=rsqrt -> CSR build (scan + fill, norm inline)
//   hw1 = x@W1                                   (f32 LDS GEMM)
//   h    = dis^2*hw1 + b1 + gather(norm*hw1)     (CSR, no atomics)
//   hagg = dis^2*relu(h) + gather(norm*relu(h))
//   [mean|lstd] = hagg @ [W2|W3] + [b2|b3]
//   zh,zl = bf16-split(mean + noise*exp(lstd))   (padded to 10112 rows)
//   out = sigmoid(z@z^T) via 3-pass bf16 MFMA: zh*zh + zh*zl + zl*zh
// d_ws: dis + zh + zl (~2.6 MB). Everything else (hw1/h/hagg/mean/lstd/CSR)
// lives in d_out's 400 MB; all dead before decode overwrites d_out.

#define Nn 10000
#define Np 10112          // 79*128, padded rows for decode
#define NpK (Np * 64)

typedef short short8 __attribute__((ext_vector_type(8)));
typedef float f32x4 __attribute__((ext_vector_type(4)));

static __device__ __forceinline__ float sigmoidf(float v) {
  return 1.0f / (1.0f + __expf(-v));
}
static __device__ __forceinline__ unsigned short f32_to_bf16(float f) {
  unsigned int u = __float_as_uint(f);
  unsigned int r = (u + 0x7FFF + ((u >> 16) & 1)) >> 16;  // RNE
  return (unsigned short)r;
}
static __device__ __forceinline__ float bf16_to_f32(unsigned short s) {
  return __uint_as_float(((unsigned int)s) << 16);
}

// deg=1 (self loop), cnt=0
__global__ void k_init(float* __restrict__ deg, int* __restrict__ cnt, int n) {
  int i = blockIdx.x * 256 + threadIdx.x;
  if (i < n) { deg[i] = 1.0f; cnt[i] = 0; }
}

__global__ void k_edge_pre(const int* __restrict__ col, const float* __restrict__ ew,
                           float* __restrict__ deg, int* __restrict__ cnt, int E) {
  int e = blockIdx.x * 256 + threadIdx.x;
  if (e < E) { int c = col[e]; atomicAdd(&deg[c], ew[e]); atomicAdd(&cnt[c], 1); }
}

__global__ void k_dis(float* __restrict__ deg, int n) {
  int i = blockIdx.x * 256 + threadIdx.x;
  if (i < n) { float d = deg[i]; deg[i] = (d > 0.0f) ? rsqrtf(d) : 0.0f; }
}

// single-block exclusive scan of cnt[0..n) -> ofs[0..n], plus copy into ofs2
__global__ __launch_bounds__(256) void k_scan(const int* __restrict__ cnt,
                                              int* __restrict__ ofs, int* __restrict__ ofs2,
                                              int n) {
  __shared__ int partial[256];
  const int t = threadIdx.x;
  const int CH = (n + 255) / 256;
  const int start = t * CH;
  int local = 0;
  for (int j = 0; j < CH; ++j) {
    int idx = start + j;
    if (idx < n) local += cnt[idx];
  }
  partial[t] = local;
  __syncthreads();
  for (int off = 1; off < 256; off <<= 1) {
    int x = (t >= off) ? partial[t - off] : 0;
    __syncthreads();
    partial[t] += x;
    __syncthreads();
  }
  int run = partial[t] - local;  // exclusive prefix
  for (int j = 0; j < CH; ++j) {
    int idx = start + j;
    if (idx < n) {
      ofs[idx] = run; ofs2[idx] = run;
      run += cnt[idx];
    }
  }
  if (t == 255) { ofs[n] = run; ofs2[n] = run; }
}

// place edges: csr_src[p]=row, csr_w[p]=dis[row]*ew*dis[col]
__global__ void k_fill(const int* __restrict__ row, const int* __restrict__ col,
                       const float* __restrict__ ew, const float* __restrict__ dis,
                       int* __restrict__ ofs2, int* __restrict__ csr_src,
                       float* __restrict__ csr_w, int E) {
  int e = blockIdx.x * 256 + threadIdx.x;
  if (e < E) {
    int r = row[e], c = col[e];
    int p = atomicAdd(&ofs2[c], 1);
    csr_src[p] = r;
    csr_w[p] = dis[r] * ew[e] * dis[c];
  }
}

// hw1 = x[10000,256] @ W1[256,128]
__global__ __launch_bounds__(256) void k_gemm1(const float* __restrict__ x,
                                               const float* __restrict__ W1,
                                               float* __restrict__ hw1) {
  __shared__ float xs[16][68];
  __shared__ float ws[64][128];
  const int tid = threadIdx.x;
  const int row0 = blockIdx.x * 16;
  const int j0 = (tid & 31) * 4;
  const int r0 = (tid >> 5) * 2;
  const int lr = tid >> 4, lk = tid & 15;
  float acc0[4] = {0, 0, 0, 0}, acc1[4] = {0, 0, 0, 0};
  for (int k0 = 0; k0 < 256; k0 += 64) {
    *(float4*)&xs[lr][lk * 4] = *(const float4*)&x[(row0 + lr) * 256 + k0 + lk * 4];
#pragma unroll
    for (int it = 0; it < 8; ++it) {
      int idx4 = tid + it * 256;
      int kk = idx4 >> 5, jq = idx4 & 31;
      *(float4*)&ws[kk][jq * 4] = *(const float4*)&W1[(k0 + kk) * 128 + jq * 4];
    }
    __syncthreads();
#pragma unroll 8
    for (int kk = 0; kk < 64; ++kk) {
      float a0 = xs[r0][kk], a1 = xs[r0 + 1][kk];
      float4 w = *(const float4*)&ws[kk][j0];
      acc0[0] += a0 * w.x; acc0[1] += a0 * w.y; acc0[2] += a0 * w.z; acc0[3] += a0 * w.w;
      acc1[0] += a1 * w.x; acc1[1] += a1 * w.y; acc1[2] += a1 * w.z; acc1[3] += a1 * w.w;
    }
    __syncthreads();
  }
  *(float4*)&hw1[(row0 + r0) * 128 + j0] = make_float4(acc0[0], acc0[1], acc0[2], acc0[3]);
  *(float4*)&hw1[(row0 + r0 + 1) * 128 + j0] = make_float4(acc1[0], acc1[1], acc1[2], acc1[3]);
}

// CSR aggregation, 4 nodes/block (1 wave each), float2 per lane.
// mode 0: out[i] = d^2*feat[i] + b + sum w*feat[src]
// mode 1: out[i] = d^2*relu(feat[i]) + sum w*relu(feat[src])
__global__ __launch_bounds__(256) void k_agg(const int* __restrict__ ofs,
                                             const int* __restrict__ csr_src,
                                             const float* __restrict__ csr_w,
                                             const float* __restrict__ feat,
                                             const float* __restrict__ dis,
                                             const float* __restrict__ b,
                                             float* __restrict__ out, int n, int relu_in) {
  int node = blockIdx.x * 4 + (threadIdx.x >> 6);
  if (node >= n) return;
  int f2 = threadIdx.x & 63;
  const float2* featv = (const float2*)feat;
  int s = ofs[node], e = ofs[node + 1];
  float d = dis[node];
  float2 self = featv[node * 64 + f2];
  float2 acc;
  if (relu_in) {
    acc.x = d * d * fmaxf(self.x, 0.0f);
    acc.y = d * d * fmaxf(self.y, 0.0f);
  } else {
    float2 bb = ((const float2*)b)[f2];
    acc.x = d * d * self.x + bb.x;
    acc.y = d * d * self.y + bb.y;
  }
  for (int j = s; j < e; ++j) {
    int r = csr_src[j];
    float wt = csr_w[j];
    float2 v = featv[r * 64 + f2];
    if (relu_in) { v.x = fmaxf(v.x, 0.0f); v.y = fmaxf(v.y, 0.0f); }
    acc.x += wt * v.x;
    acc.y += wt * v.y;
  }
  ((float2*)out)[node * 64 + f2] = acc;
}

// [mean|lstd] = hagg[10000,128] @ [W2|W3][128,64] + [b2|b3]
__global__ __launch_bounds__(256) void k_gemm2(const float* __restrict__ hagg,
                                               const float* __restrict__ W2, const float* __restrict__ W3,
                                               const float* __restrict__ b2, const float* __restrict__ b3,
                                               float* __restrict__ mean, float* __restrict__ lstd) {
  __shared__ float xs[16][68];
  __shared__ float ws[64][128];
  const int tid = threadIdx.x;
  const int row0 = blockIdx.x * 16;
  const int j0 = (tid & 31) * 4;
  const int r0 = (tid >> 5) * 2;
  const int lr = tid >> 4, lk = tid & 15;
  float acc0[4] = {0, 0, 0, 0}, acc1[4] = {0, 0, 0, 0};
  for (int k0 = 0; k0 < 128; k0 += 64) {
    *(float4*)&xs[lr][lk * 4] = *(const float4*)&hagg[(row0 + lr) * 128 + k0 + lk * 4];
#pragma unroll
    for (int it = 0; it < 8; ++it) {
      int idx4 = tid + it * 256;
      int kk = idx4 >> 5, jq = idx4 & 31;
      int j = jq * 4;
      float4 wv;
      if (j < 64) wv = *(const float4*)&W2[(k0 + kk) * 64 + j];
      else        wv = *(const float4*)&W3[(k0 + kk) * 64 + (j - 64)];
      *(float4*)&ws[kk][j] = wv;
    }
    __syncthreads();
#pragma unroll 8
    for (int kk = 0; kk < 64; ++kk) {
      float a0 = xs[r0][kk], a1 = xs[r0 + 1][kk];
      float4 w = *(const float4*)&ws[kk][j0];
      acc0[0] += a0 * w.x; acc0[1] += a0 * w.y; acc0[2] += a0 * w.z; acc0[3] += a0 * w.w;
      acc1[0] += a1 * w.x; acc1[1] += a1 * w.y; acc1[2] += a1 * w.z; acc1[3] += a1 * w.w;
    }
    __syncthreads();
  }
  if (j0 < 64) {
    float4 bb = *(const float4*)&b2[j0];
    *(float4*)&mean[(row0 + r0) * 64 + j0] =
        make_float4(acc0[0] + bb.x, acc0[1] + bb.y, acc0[2] + bb.z, acc0[3] + bb.w);
    *(float4*)&mean[(row0 + r0 + 1) * 64 + j0] =
        make_float4(acc1[0] + bb.x, acc1[1] + bb.y, acc1[2] + bb.z, acc1[3] + bb.w);
  } else {
    int j = j0 - 64;
    float4 bb = *(const float4*)&b3[j];
    *(float4*)&lstd[(row0 + r0) * 64 + j] =
        make_float4(acc0[0] + bb.x, acc0[1] + bb.y, acc0[2] + bb.z, acc0[3] + bb.w);
    *(float4*)&lstd[(row0 + r0 + 1) * 64 + j] =
        make_float4(acc1[0] + bb.x, acc1[1] + bb.y, acc1[2] + bb.z, acc1[3] + bb.w);
  }
}

// z = mean + noise*exp(lstd), split into bf16 hi/lo, zero-pad rows n..Np
__global__ void k_zsplit(const float* __restrict__ mean, const float* __restrict__ lstd,
                         const float* __restrict__ noise,
                         unsigned short* __restrict__ zh, unsigned short* __restrict__ zl) {
  int idx = blockIdx.x * 256 + threadIdx.x;
  if (idx < NpK) {
    float v = 0.0f;
    if (idx < Nn * 64) v = mean[idx] + noise[idx] * __expf(lstd[idx]);
    unsigned short h = f32_to_bf16(v);
    float lo = v - bf16_to_f32(h);
    zh[idx] = h;
    zl[idx] = f32_to_bf16(lo);
  }
}

// out = sigmoid(z@z^T), 128x128 tile / 4 waves, each wave 64x64 via 4x4 of
// 16x16x32 bf16 MFMA; K-passes: zh*zh, zh*zl, zl*zh. Fragments straight from
// global (zh/zl = 2.6 MB, L2-resident).
__global__ __launch_bounds__(256) void k_decode(const unsigned short* __restrict__ zh,
                                                const unsigned short* __restrict__ zl,
                                                float* __restrict__ out, int n) {
  const int tid = threadIdx.x;
  const int wave = tid >> 6, lane = tid & 63;
  const int rows0 = blockIdx.y * 128 + (wave >> 1) * 64;
  const int cols0 = blockIdx.x * 128 + (wave & 1) * 64;
  const int lrow = lane & 15;   // A row / B col within 16-tile
  const int quad = lane >> 4;   // k = quad*8 + j
  f32x4 acc[4][4];
#pragma unroll
  for (int m = 0; m < 4; ++m)
#pragma unroll
    for (int nn = 0; nn < 4; ++nn) acc[m][nn] = (f32x4){0.0f, 0.0f, 0.0f, 0.0f};

#pragma unroll
  for (int s = 0; s < 3; ++s) {
    const unsigned short* A = (s == 2) ? zl : zh;
    const unsigned short* B = (s == 1) ? zl : zh;
#pragma unroll
    for (int kc = 0; kc < 64; kc += 32) {
      const int ko = kc + quad * 8;
      short8 af[4], bf[4];
#pragma unroll
      for (int m = 0; m < 4; ++m)
        af[m] = *(const short8*)&A[(rows0 + m * 16 + lrow) * 64 + ko];
#pragma unroll
      for (int nn = 0; nn < 4; ++nn)
        bf[nn] = *(const short8*)&B[(cols0 + nn * 16 + lrow) * 64 + ko];
#pragma unroll
      for (int m = 0; m < 4; ++m)
#pragma unroll
        for (int nn = 0; nn < 4; ++nn)
          acc[m][nn] = __builtin_amdgcn_mfma_f32_16x16x32_bf16(af[m], bf[nn], acc[m][nn], 0, 0, 0);
    }
  }

  // C layout: col = lane&15, row = quad*4 + reg
  const int crow0 = quad * 4;
#pragma unroll
  for (int m = 0; m < 4; ++m) {
#pragma unroll
    for (int nn = 0; nn < 4; ++nn) {
      int gc = cols0 + nn * 16 + lrow;
      if (gc >= n) continue;
#pragma unroll
      for (int r = 0; r < 4; ++r) {
        int gr = rows0 + m * 16 + crow0 + r;
        if (gr < n) out[(size_t)gr * n + gc] = sigmoidf(acc[m][nn][r]);
      }
    }
  }
}

extern "C" void kernel_launch(void* const* d_in, const int* in_sizes, int n_in,
                              void* d_out, int out_size, void* d_ws, size_t ws_size,
                              hipStream_t stream) {
  const float* x     = (const float*)d_in[0];
  const int*   ei    = (const int*)d_in[1];
  const float* ew    = (const float*)d_in[2];
  const float* noise = (const float*)d_in[3];
  const float* W1    = (const float*)d_in[4];
  const float* b1    = (const float*)d_in[5];
  const float* W2    = (const float*)d_in[6];
  const float* b2    = (const float*)d_in[7];
  const float* W3    = (const float*)d_in[8];
  const float* b3    = (const float*)d_in[9];
  const int E = in_sizes[2];
  const int n = Nn;
  const int* row = ei;
  const int* col = ei + E;

  // d_ws: dis (40 KB) + zh + zl (2.6 MB)
  float* dis = (float*)d_ws;
  unsigned short* zh = (unsigned short*)((char*)d_ws + 10240 * 4);
  unsigned short* zl = zh + NpK;

  // big scratch in d_out (all dead before k_decode rewrites d_out)
  float* S    = (float*)d_out;
  float* hw1  = S;                         // n*128
  float* h    = S + 1310720;               // n*128
  float* hagg = S + 2621440;               // n*128
  float* mean = S + 3932160;               // n*64
  float* lstd = S + 4587520;               // n*64
  float* csr_w  = S + 5242880;             // E
  int* csr_src  = (int*)(S + 5402880);     // E
  int* ofs      = (int*)(S + 5562880);     // n+1
  int* ofs2     = (int*)(S + 5572896);     // n+1
  int* cnt      = (int*)(S + 5582912);     // n

  k_init<<<(n + 255) / 256, 256, 0, stream>>>(dis, cnt, n);
  k_edge_pre<<<(E + 255) / 256, 256, 0, stream>>>(col, ew, dis, cnt, E);
  k_dis<<<(n + 255) / 256, 256, 0, stream>>>(dis, n);
  k_scan<<<1, 256, 0, stream>>>(cnt, ofs, ofs2, n);
  k_fill<<<(E + 255) / 256, 256, 0, stream>>>(row, col, ew, dis, ofs2, csr_src, csr_w, E);

  k_gemm1<<<n / 16, 256, 0, stream>>>(x, W1, hw1);
  k_agg<<<(n + 3) / 4, 256, 0, stream>>>(ofs, csr_src, csr_w, hw1, dis, b1, h, n, 0);
  k_agg<<<(n + 3) / 4, 256, 0, stream>>>(ofs, csr_src, csr_w, h, dis, b1, hagg, n, 1);

  k_gemm2<<<n / 16, 256, 0, stream>>>(hagg, W2, W3, b2, b3, mean, lstd);
  k_zsplit<<<(NpK + 255) / 256, 256, 0, stream>>>(mean, lstd, noise, zh, zl);

  dim3 g((n + 127) / 128, (n + 127) / 128);
  k_decode<<<g, 256, 0, stream>>>(zh, zl, (float*)d_out, n);
}